// Round 3
// baseline (1293.441 us; speedup 1.0000x reference)
//
#include <hip/hip_runtime.h>

// Synonym: top-5 cosine similarity, 512 queries x 400000x300 fp32 table.
// v4 pipeline:
//   P0a qprep  : gather+normalize query rows -> qf (fp32) + qsw (bf16,
//                B-fragment-swizzled, K-pad 320)
//   P0b prenorm: table -> row-normalized bf16, A-frag swizzled. Reads staged
//                through LDS (fully coalesced f32x4 streams).
//   P1  score  : 512-thr blocks (8 waves = 4 rowpairs x 2 qhalves), 128-query
//                LDS panel (81,920 B -> 2 blocks/CU, 16 waves/CU). Wave owns
//                2 tiles x 64 queries -> acc[4][2] (32 AGPR), total regs <=128
//                (no spill, unlike v3). 2-deep ks prefetch of A-frags hides
//                HBM latency. Stripe pinned to XCD (bid&7) for 4x m-reuse.
//   P2  topk   : scan 3072 cands/query -> top-32 -> exact fp32 rescore -> top-5

#define VOCAB   400000
#define DIM     300
#define NQ      512
#define NT      25000      // 16-row tiles
#define TILE_U  5120       // u16 per swizzled tile (10 ksteps * 512)
#define QFSTR   304        // fp32 query row stride
#define TOPK    5
#define NCAND   3072       // per-query cand slots: 128 stripe * 4 rowpair * 6

using f32x4 = __attribute__((ext_vector_type(4))) float;
using s16x8 = __attribute__((ext_vector_type(8))) short;

__device__ __forceinline__ unsigned short f2bf(float f) {
  unsigned int u = __builtin_bit_cast(unsigned int, f);
  u += 0x7fffu + ((u >> 16) & 1u);   // RNE to bf16
  return (unsigned short)(u >> 16);
}

__device__ __forceinline__ void ins3(float v, int id, float* tv, int* ti) {
  if (v > tv[2]) {
    if (v > tv[0]) {
      tv[2] = tv[1]; ti[2] = ti[1]; tv[1] = tv[0]; ti[1] = ti[0];
      tv[0] = v; ti[0] = id;
    } else if (v > tv[1]) {
      tv[2] = tv[1]; ti[2] = ti[1]; tv[1] = v; ti[1] = id;
    } else {
      tv[2] = v; ti[2] = id;
    }
  }
}

// ---------------- P0a: query gather + normalize ----------------
// qsw layout (B-fragment order): element (q, k=ks*32+grp*8+j) at u16 offset
// (q>>4)*TILE_U + ks*512 + grp*128 + (q&15)*8 + j.
__global__ __launch_bounds__(64)
void qprep_kernel(const float* __restrict__ emb, const int* __restrict__ wid,
                  float* __restrict__ qf, unsigned short* __restrict__ qsw) {
  const int q = blockIdx.x;
  const int lane = threadIdx.x;
  const long long w = (long long)wid[q];
  const float* row = emb + w * DIM;
  float x[5];
  double ss = 0.0;
#pragma unroll
  for (int j = 0; j < 5; ++j) {
    const int k = lane + 64 * j;
    x[j] = (k < DIM) ? row[k] : 0.0f;
    ss += (double)x[j] * (double)x[j];
  }
#pragma unroll
  for (int m = 1; m < 64; m <<= 1) ss += __shfl_xor(ss, m, 64);
  const double rinv = 1.0 / sqrt(ss);
#pragma unroll
  for (int j = 0; j < 5; ++j) {
    const int k = lane + 64 * j;
    if (k < DIM) qf[q * QFSTR + k] = (float)((double)x[j] * rinv);
  }
  // swizzled bf16 write: lanes 0..39 each own one (ks,grp) 8-chunk
  if (lane < 40) {
    const int ks = lane >> 2, grp = lane & 3;
    const int k0 = ks * 32 + grp * 8;
    unsigned int pw[4];
#pragma unroll
    for (int h = 0; h < 4; ++h) {
      const int k = k0 + 2 * h;
      float v0 = 0.f, v1 = 0.f;
      if (k < DIM)     v0 = (float)((double)row[k] * rinv);
      if (k + 1 < DIM) v1 = (float)((double)row[k + 1] * rinv);
      pw[h] = (unsigned int)f2bf(v0) | ((unsigned int)f2bf(v1) << 16);
    }
    uint4 pk; pk.x = pw[0]; pk.y = pw[1]; pk.z = pw[2]; pk.w = pw[3];
    *(uint4*)(qsw + (size_t)(q >> 4) * TILE_U + ks * 512 + grp * 128 + (q & 15) * 8) = pk;
  }
}

// ---------------- P0b: table -> normalized bf16, A-frag swizzled ----------------
// Block handles 4 tiles (64 rows, 76,800 B) staged into LDS with coalesced
// f32x4 reads, then each wave computes one tile's swizzle from LDS.
// Swizzle: tile t, element (row=t*16+r, k=ks*32+grp*8+j) at u16 offset
// t*5120 + ks*512 + grp*128 + r*8 + j.
__global__ __launch_bounds__(256)
void prenorm_kernel(const float* __restrict__ emb, unsigned short* __restrict__ sw) {
  __shared__ __align__(16) float rows[64 * 300];   // 76,800 B

  const int tid = threadIdx.x;
  const int bid = blockIdx.x;
  // coalesced stage of 64 rows (4800 f32x4)
  {
    const f32x4* src = (const f32x4*)(emb + (size_t)bid * 64 * 300);
    f32x4* dst = (f32x4*)rows;
#pragma unroll
    for (int i = 0; i < 19; ++i) {
      const int idx = tid + 256 * i;
      if (idx < 4800) dst[idx] = src[idx];
    }
  }
  __syncthreads();

  const int wave = tid >> 6, lane = tid & 63;
  const int t = bid * 4 + wave;
  const int r = lane & 15, grp = lane >> 4;
  const float* row = rows + (wave * 16 + r) * 300;

  float x[10][8];
  float ss = 0.f;
#pragma unroll
  for (int ks = 0; ks < 10; ++ks) {
    const int k0 = ks * 32 + grp * 8;
    if (k0 + 8 <= DIM) {
      const f32x4 u = *(const f32x4*)(row + k0);
      const f32x4 v = *(const f32x4*)(row + k0 + 4);
#pragma unroll
      for (int j = 0; j < 4; ++j) { x[ks][j] = u[j]; x[ks][j + 4] = v[j]; }
    } else {
#pragma unroll
      for (int j = 0; j < 8; ++j) {
        const int k = k0 + j;
        x[ks][j] = (k < DIM) ? row[k] : 0.0f;
      }
    }
#pragma unroll
    for (int j = 0; j < 8; ++j) ss += x[ks][j] * x[ks][j];
  }
  // row sumsq: partners are lanes r, r+16, r+32, r+48
  ss += __shfl_xor(ss, 16, 64);
  ss += __shfl_xor(ss, 32, 64);
  const float rinv = rsqrtf(ss);

  unsigned short* dst = sw + (size_t)t * TILE_U + lane * 8;
#pragma unroll
  for (int ks = 0; ks < 10; ++ks) {
    uint4 pk;
    unsigned int w0 = f2bf(x[ks][0] * rinv) | ((unsigned int)f2bf(x[ks][1] * rinv) << 16);
    unsigned int w1 = f2bf(x[ks][2] * rinv) | ((unsigned int)f2bf(x[ks][3] * rinv) << 16);
    unsigned int w2 = f2bf(x[ks][4] * rinv) | ((unsigned int)f2bf(x[ks][5] * rinv) << 16);
    unsigned int w3 = f2bf(x[ks][6] * rinv) | ((unsigned int)f2bf(x[ks][7] * rinv) << 16);
    pk.x = w0; pk.y = w1; pk.z = w2; pk.w = w3;
    *(uint4*)(dst + ks * 512) = pk;
  }
}

// ---------------- P1: MFMA score + windowed candidates ----------------
// Grid 512 blocks x 512 threads. bid = (s&7) + 8*(m + 4*(s>>3)):
//   m = query panel (128 q), s = row stripe (0..127). Stripe pinned to XCD
//   s&7 so the 4 m-blocks sharing tiles hit one L2 (per-XCD/iter: 1.28 MB).
// Wave = rowpair wr (w>>1) x qhalf (w&1): 2 tiles x 64 queries -> acc[4][2].
// Per iter block covers 8 tiles (stripe s); 24 full iters = 24576 tiles,
// tail iter only for s<53 (424 tiles) -> 25000 exact.
__global__ __launch_bounds__(512, 4)
void score_kernel(const unsigned short* __restrict__ sw,
                  const unsigned short* __restrict__ qsw,
                  float2* __restrict__ cand) {
  __shared__ __align__(16) unsigned short qlds[8 * TILE_U];   // 81,920 B

  const int tid = threadIdx.x;
  const int wave = tid >> 6, lane = tid & 63;
  const int l15 = lane & 15, grp = lane >> 4;
  const int bid = blockIdx.x;
  const int rest = bid >> 3;
  const int m = rest & 3;
  const int s = (bid & 7) | ((rest >> 2) << 3);   // 0..127
  const int wr = wave >> 1, qhalf = wave & 1;

  // stage the 128-query B-panel (8 q-tiles) once
  {
    const uint4* src = (const uint4*)(qsw + (size_t)m * 8 * TILE_U);
    uint4* dst = (uint4*)qlds;
#pragma unroll
    for (int i = 0; i < 10; ++i) dst[tid + 512 * i] = src[tid + 512 * i];
  }
  __syncthreads();

  float v3[4][3]; int i3[4][3];
#pragma unroll
  for (int qi = 0; qi < 4; ++qi)
#pragma unroll
    for (int j = 0; j < 3; ++j) { v3[qi][j] = -1e30f; i3[qi][j] = 0; }

  const unsigned short* aw = sw + lane * 8;
  const unsigned short* bw = qlds + (size_t)qhalf * 4 * TILE_U + lane * 8;
  const int wt = s * 8 + wr * 2;                  // wave's first tile in stripe
  const int nit = (s < 53) ? 25 : 24;             // 24*1024 + 424 = 25000

  // 2-deep ks prefetch, parity double-buffer (static indices under unroll)
  s16x8 ab[2][2];
  {
    const unsigned w0 = (unsigned)wt * TILE_U;
    ab[0][0] = *(const s16x8*)(aw + w0);
    ab[0][1] = *(const s16x8*)(aw + w0 + TILE_U);
    ab[1][0] = *(const s16x8*)(aw + w0 + 512);
    ab[1][1] = *(const s16x8*)(aw + w0 + TILE_U + 512);
  }

  for (int it = 0; it < nit; ++it) {
    const int t0 = it * 1024 + wt;
    const unsigned toff = (unsigned)t0 * TILE_U;

    f32x4 acc[4][2];
#pragma unroll
    for (int qi = 0; qi < 4; ++qi) {
      acc[qi][0] = {0.f, 0.f, 0.f, 0.f};
      acc[qi][1] = {0.f, 0.f, 0.f, 0.f};
    }

#pragma unroll
    for (int ks = 0; ks < 10; ++ks) {
      // issue prefetch for ks+2 (or next iter's ks0/ks1; dummy tile wt at end)
      unsigned poff;
      if (ks < 8) {
        poff = toff + (unsigned)(ks + 2) * 512;
      } else {
        const unsigned ntoff =
            (it + 1 < nit) ? toff + 1024u * TILE_U : (unsigned)wt * TILE_U;
        poff = ntoff + (unsigned)(ks - 8) * 512;
      }
      const s16x8 p0 = *(const s16x8*)(aw + poff);
      const s16x8 p1 = *(const s16x8*)(aw + poff + TILE_U);

      const unsigned short* bb = bw + ks * 512;
#pragma unroll
      for (int qi = 0; qi < 4; ++qi) {
        const s16x8 b = *(const s16x8*)(bb + qi * TILE_U);
        acc[qi][0] = __builtin_amdgcn_mfma_f32_16x16x32_bf16(ab[ks & 1][0], b, acc[qi][0], 0, 0, 0);
        acc[qi][1] = __builtin_amdgcn_mfma_f32_16x16x32_bf16(ab[ks & 1][1], b, acc[qi][1], 0, 0, 0);
      }
      ab[ks & 1][0] = p0;
      ab[ks & 1][1] = p1;
    }

    // scan acc -> per-lane top-3, gated by 4-wide max
    // (C/D layout: row = tile*16 + grp*4 + rr, col = query l15)
#pragma unroll
    for (int vi = 0; vi < 2; ++vi) {
      const int rbase = (t0 + vi) * 16 + grp * 4;
#pragma unroll
      for (int qi = 0; qi < 4; ++qi) {
        const f32x4 a4 = acc[qi][vi];
        const float m01 = fmaxf(a4[0], a4[1]);
        const float m23 = fmaxf(a4[2], a4[3]);
        if (fmaxf(m01, m23) > v3[qi][2]) {
#pragma unroll
          for (int rr = 0; rr < 4; ++rr)
            ins3(a4[rr], rbase + rr, &v3[qi][0], &i3[qi][0]);
        }
      }
    }
  }

  // merge 4 grp-lanes' top-3 -> union top-6, write 6 cand slots per
  // (query, stripe, rowpair)
#pragma unroll
  for (int qi = 0; qi < 4; ++qi) {
    float m0 = v3[qi][0], m1 = v3[qi][1], m2 = v3[qi][2];
    int   d0 = i3[qi][0], d1 = i3[qi][1], d2 = i3[qi][2];
    const int q = m * 128 + qhalf * 64 + qi * 16 + l15;
    float2* dst = cand + (size_t)q * NCAND + ((s * 4 + wr) * 6);
#pragma unroll
    for (int r = 0; r < 6; ++r) {
      float bv = m0; int bi = d0; int bl = grp;
      float ov = __shfl_xor(bv, 16, 64);
      int   oi = __shfl_xor(bi, 16, 64);
      int   ol = __shfl_xor(bl, 16, 64);
      if (ov > bv || (ov == bv && ol < bl)) { bv = ov; bi = oi; bl = ol; }
      ov = __shfl_xor(bv, 32, 64);
      oi = __shfl_xor(bi, 32, 64);
      ol = __shfl_xor(bl, 32, 64);
      if (ov > bv || (ov == bv && ol < bl)) { bv = ov; bi = oi; bl = ol; }
      if (bl == grp) { m0 = m1; d0 = d1; m1 = m2; d1 = d2; m2 = -1e30f; }
      if (r == grp || r == grp + 4) {
        float2 e; e.x = bv; e.y = __int_as_float(bi);
        dst[r] = e;
      }
    }
  }
}

// ---------------- P2: merge candidates, exact rescore, top-5 ----------------
__global__ __launch_bounds__(256)
void topk_kernel(const float* __restrict__ emb, const float* __restrict__ qf,
                 const float2* __restrict__ cand, float* __restrict__ out) {
  __shared__ float pV[256 * 6];
  __shared__ int   pI[256 * 6];
  __shared__ int   selI[32];
  __shared__ float resV[32];

  const int q = blockIdx.x;
  const int t = threadIdx.x;
  const float2* cq = cand + (size_t)q * NCAND;

  // per-thread top-6 over 3072/256 = 12 entries
  float bv[6]; int bi[6];
#pragma unroll
  for (int j = 0; j < 6; ++j) { bv[j] = -1e30f; bi[j] = -1; }
  for (int i = t; i < NCAND; i += 256) {
    const float2 e = cq[i];
    const float v = e.x;
    if (v > bv[5]) {
      bv[5] = v; bi[5] = __float_as_int(e.y);
#pragma unroll
      for (int j = 5; j > 0; --j) {
        if (bv[j] > bv[j - 1]) {
          const float tv2 = bv[j]; bv[j] = bv[j - 1]; bv[j - 1] = tv2;
          const int ti2 = bi[j]; bi[j] = bi[j - 1]; bi[j - 1] = ti2;
        }
      }
    }
  }
#pragma unroll
  for (int j = 0; j < 6; ++j) { pV[t * 6 + j] = bv[j]; pI[t * 6 + j] = bi[j]; }
  __syncthreads();

  // wave 0: select top-32 (approx values) from the 1536-entry pool
  if (t < 64) {
    for (int r = 0; r < 32; ++r) {
      float mv = -2e30f; int mp = 0;
      for (int i = t; i < 256 * 6; i += 64) {
        const float v = pV[i];
        if (v > mv) { mv = v; mp = i; }
      }
#pragma unroll
      for (int m = 1; m < 64; m <<= 1) {
        const float ov = __shfl_xor(mv, m, 64);
        const int   op = __shfl_xor(mp, m, 64);
        if (ov > mv) { mv = ov; mp = op; }
      }
      if (t == 0) { selI[r] = pI[mp]; pV[mp] = -2e30f; }
      __builtin_amdgcn_wave_barrier();
    }
  }
  __syncthreads();

  // exact fp32 rescore of 32 candidates, 8 threads each
  {
    const int j = t >> 3, sub = t & 7;
    const int id = selI[j];
    float dot = 0.f, sq = 0.f;
    if (id >= 0) {
      const f32x4* e4 = (const f32x4*)(emb + (size_t)id * DIM);
      const f32x4* q4 = (const f32x4*)(qf + (size_t)q * QFSTR);
      for (int f = sub; f < DIM / 4; f += 8) {
        const f32x4 ev = e4[f], qv = q4[f];
        dot += ev[0]*qv[0] + ev[1]*qv[1] + ev[2]*qv[2] + ev[3]*qv[3];
        sq  += ev[0]*ev[0] + ev[1]*ev[1] + ev[2]*ev[2] + ev[3]*ev[3];
      }
    }
#pragma unroll
    for (int m = 1; m < 8; m <<= 1) {
      dot += __shfl_xor(dot, m, 64);
      sq  += __shfl_xor(sq, m, 64);
    }
    if (sub == 0)
      resV[j] = (id >= 0 && sq > 0.f) ? (float)((double)dot / sqrt((double)sq)) : -2e30f;
  }
  __syncthreads();

  if (t == 0) {
#pragma unroll
    for (int r = 0; r < TOPK; ++r) {
      float mv = -3e30f; int mp = 0;
      for (int i = 0; i < 32; ++i) if (resV[i] > mv) { mv = resV[i]; mp = i; }
      out[q * TOPK + r] = mv;
      out[NQ * TOPK + q * TOPK + r] = (float)selI[mp];
      resV[mp] = -3e30f;
    }
  }
}

extern "C" void kernel_launch(void* const* d_in, const int* in_sizes, int n_in,
                              void* d_out, int out_size, void* d_ws, size_t ws_size,
                              hipStream_t stream) {
  (void)in_sizes; (void)n_in; (void)out_size; (void)ws_size;
  const float* emb = (const float*)d_in[0];
  const int* wid = (const int*)d_in[1];   // word_ids; d_in[2] (k=5) hardcoded
  float* out = (float*)d_out;

  // workspace layout (total 269,533,184 B):
  //   qsw  @ 0         : 32*5120*2   =    327,680
  //   qf   @ 327680    : 512*304*4   =    622,592
  //   cand @ 950272    : 512*3072*8  = 12,582,912
  //   sw   @ 13533184  : 25000*10240 = 256,000,000
  char* ws = (char*)d_ws;
  unsigned short* qsw = (unsigned short*)ws;
  float*  qf   = (float*)(ws + 327680);
  float2* cand = (float2*)(ws + 950272);
  unsigned short* sw = (unsigned short*)(ws + 13533184);

  qprep_kernel<<<NQ, 64, 0, stream>>>(emb, wid, qf, qsw);
  prenorm_kernel<<<VOCAB / 64, 256, 0, stream>>>(emb, sw);
  score_kernel<<<512, 512, 0, stream>>>(sw, qsw, cand);
  topk_kernel<<<NQ, 256, 0, stream>>>(emb, qf, cand, out);
}

// Round 4
// 1093.154 us; speedup vs baseline: 1.1832x; 1.1832x over previous
//
#include <hip/hip_runtime.h>

// Synonym: top-5 cosine similarity, 512 queries x 400000x300 fp32 table.
// v5 pipeline:
//   P0a qprep  : gather+normalize query rows -> qf (fp32) + qsw (bf16,
//                B-fragment-swizzled, K-pad 320)
//   P0b prenorm: table -> row-normalized bf16, A-frag swizzled, LDS-staged
//                coalesced reads.
//   P1  score  : 512-thr blocks, 128-query LDS panel (81,920 B). Wave owns
//                2 tiles x 64 q (acc[4][2]). __launch_bounds__(512,2): 256-reg
//                budget, NO forced occupancy (v3/v4's caps caused spills).
//                Full-tile-pair register prefetch (2 banks x 2 tiles x 10 ks
//                = 160 VGPR): ~880-cycle prefetch distance hides HBM latency.
//                Stripe pinned to XCD (bid&7) for cross-m L2 reuse.
//   P2  topk   : scan 3072 cands/query -> top-32 -> exact fp32 rescore -> top-5

#define VOCAB   400000
#define DIM     300
#define NQ      512
#define NT      25000      // 16-row tiles
#define TILE_U  5120       // u16 per swizzled tile (10 ksteps * 512)
#define QFSTR   304        // fp32 query row stride
#define TOPK    5
#define NCAND   3072       // per-query cand slots: 128 stripe * 4 rowpair * 6

using f32x4 = __attribute__((ext_vector_type(4))) float;
using s16x8 = __attribute__((ext_vector_type(8))) short;

__device__ __forceinline__ unsigned short f2bf(float f) {
  unsigned int u = __builtin_bit_cast(unsigned int, f);
  u += 0x7fffu + ((u >> 16) & 1u);   // RNE to bf16
  return (unsigned short)(u >> 16);
}

__device__ __forceinline__ void ins3(float v, int id, float* tv, int* ti) {
  if (v > tv[2]) {
    if (v > tv[0]) {
      tv[2] = tv[1]; ti[2] = ti[1]; tv[1] = tv[0]; ti[1] = ti[0];
      tv[0] = v; ti[0] = id;
    } else if (v > tv[1]) {
      tv[2] = tv[1]; ti[2] = ti[1]; tv[1] = v; ti[1] = id;
    } else {
      tv[2] = v; ti[2] = id;
    }
  }
}

// ---------------- P0a: query gather + normalize ----------------
// qsw layout (B-fragment order): element (q, k=ks*32+grp*8+j) at u16 offset
// (q>>4)*TILE_U + ks*512 + grp*128 + (q&15)*8 + j.
__global__ __launch_bounds__(64)
void qprep_kernel(const float* __restrict__ emb, const int* __restrict__ wid,
                  float* __restrict__ qf, unsigned short* __restrict__ qsw) {
  const int q = blockIdx.x;
  const int lane = threadIdx.x;
  const long long w = (long long)wid[q];
  const float* row = emb + w * DIM;
  float x[5];
  double ss = 0.0;
#pragma unroll
  for (int j = 0; j < 5; ++j) {
    const int k = lane + 64 * j;
    x[j] = (k < DIM) ? row[k] : 0.0f;
    ss += (double)x[j] * (double)x[j];
  }
#pragma unroll
  for (int m = 1; m < 64; m <<= 1) ss += __shfl_xor(ss, m, 64);
  const double rinv = 1.0 / sqrt(ss);
#pragma unroll
  for (int j = 0; j < 5; ++j) {
    const int k = lane + 64 * j;
    if (k < DIM) qf[q * QFSTR + k] = (float)((double)x[j] * rinv);
  }
  // swizzled bf16 write: lanes 0..39 each own one (ks,grp) 8-chunk
  if (lane < 40) {
    const int ks = lane >> 2, grp = lane & 3;
    const int k0 = ks * 32 + grp * 8;
    unsigned int pw[4];
#pragma unroll
    for (int h = 0; h < 4; ++h) {
      const int k = k0 + 2 * h;
      float v0 = 0.f, v1 = 0.f;
      if (k < DIM)     v0 = (float)((double)row[k] * rinv);
      if (k + 1 < DIM) v1 = (float)((double)row[k + 1] * rinv);
      pw[h] = (unsigned int)f2bf(v0) | ((unsigned int)f2bf(v1) << 16);
    }
    uint4 pk; pk.x = pw[0]; pk.y = pw[1]; pk.z = pw[2]; pk.w = pw[3];
    *(uint4*)(qsw + (size_t)(q >> 4) * TILE_U + ks * 512 + grp * 128 + (q & 15) * 8) = pk;
  }
}

// ---------------- P0b: table -> normalized bf16, A-frag swizzled ----------------
// Block handles 4 tiles (64 rows, 76,800 B) staged into LDS with coalesced
// f32x4 reads, then each wave computes one tile's swizzle from LDS.
__global__ __launch_bounds__(256)
void prenorm_kernel(const float* __restrict__ emb, unsigned short* __restrict__ sw) {
  __shared__ __align__(16) float rows[64 * 300];   // 76,800 B

  const int tid = threadIdx.x;
  const int bid = blockIdx.x;
  // coalesced stage of 64 rows (4800 f32x4)
  {
    const f32x4* src = (const f32x4*)(emb + (size_t)bid * 64 * 300);
    f32x4* dst = (f32x4*)rows;
#pragma unroll
    for (int i = 0; i < 19; ++i) {
      const int idx = tid + 256 * i;
      if (idx < 4800) dst[idx] = src[idx];
    }
  }
  __syncthreads();

  const int wave = tid >> 6, lane = tid & 63;
  const int t = bid * 4 + wave;
  const int r = lane & 15, grp = lane >> 4;
  const float* row = rows + (wave * 16 + r) * 300;

  float x[10][8];
  float ss = 0.f;
#pragma unroll
  for (int ks = 0; ks < 10; ++ks) {
    const int k0 = ks * 32 + grp * 8;
    if (k0 + 8 <= DIM) {
      const f32x4 u = *(const f32x4*)(row + k0);
      const f32x4 v = *(const f32x4*)(row + k0 + 4);
#pragma unroll
      for (int j = 0; j < 4; ++j) { x[ks][j] = u[j]; x[ks][j + 4] = v[j]; }
    } else {
#pragma unroll
      for (int j = 0; j < 8; ++j) {
        const int k = k0 + j;
        x[ks][j] = (k < DIM) ? row[k] : 0.0f;
      }
    }
#pragma unroll
    for (int j = 0; j < 8; ++j) ss += x[ks][j] * x[ks][j];
  }
  // row sumsq: partners are lanes r, r+16, r+32, r+48
  ss += __shfl_xor(ss, 16, 64);
  ss += __shfl_xor(ss, 32, 64);
  const float rinv = rsqrtf(ss);

  unsigned short* dst = sw + (size_t)t * TILE_U + lane * 8;
#pragma unroll
  for (int ks = 0; ks < 10; ++ks) {
    uint4 pk;
    unsigned int w0 = f2bf(x[ks][0] * rinv) | ((unsigned int)f2bf(x[ks][1] * rinv) << 16);
    unsigned int w1 = f2bf(x[ks][2] * rinv) | ((unsigned int)f2bf(x[ks][3] * rinv) << 16);
    unsigned int w2 = f2bf(x[ks][4] * rinv) | ((unsigned int)f2bf(x[ks][5] * rinv) << 16);
    unsigned int w3 = f2bf(x[ks][6] * rinv) | ((unsigned int)f2bf(x[ks][7] * rinv) << 16);
    pk.x = w0; pk.y = w1; pk.z = w2; pk.w = w3;
    *(uint4*)(dst + ks * 512) = pk;
  }
}

// ---------------- P1: MFMA score, deep-prefetch, windowed candidates ----------------
// Grid 512 blocks x 512 threads. bid = (s&7) + 8*(m + 4*(s>>3)):
//   m = query panel (128 q), s = row stripe (0..127), stripe pinned to XCD.
// Wave = rowpair wr (w>>1) x qhalf (w&1): tiles {s*8+wr*2, +1} stepping 1024
// tiles/iter. 24 full iters = 24576 tiles; tail iter for wt<424 -> 25000.
// Double-banked full-pair register prefetch: bank = 2 tiles x 10 ks s16x8.

__device__ __forceinline__ void load_bank(s16x8 (&bank)[2][10],
                                          const unsigned short* __restrict__ aw,
                                          unsigned toff) {
#pragma unroll
  for (int ks = 0; ks < 10; ++ks) {
    bank[0][ks] = *(const s16x8*)(aw + toff + ks * 512);
    bank[1][ks] = *(const s16x8*)(aw + toff + TILE_U + ks * 512);
  }
}

__device__ __forceinline__ void compute_pair(const s16x8 (&bank)[2][10],
                                             const unsigned short* __restrict__ bw,
                                             int t0, int grp,
                                             float (&v3)[4][3], int (&i3)[4][3]) {
  f32x4 acc[4][2];
#pragma unroll
  for (int qi = 0; qi < 4; ++qi) {
    acc[qi][0] = {0.f, 0.f, 0.f, 0.f};
    acc[qi][1] = {0.f, 0.f, 0.f, 0.f};
  }
#pragma unroll
  for (int ks = 0; ks < 10; ++ks) {
    const unsigned short* bb = bw + ks * 512;
#pragma unroll
    for (int qi = 0; qi < 4; ++qi) {
      const s16x8 b = *(const s16x8*)(bb + qi * TILE_U);
      acc[qi][0] = __builtin_amdgcn_mfma_f32_16x16x32_bf16(bank[0][ks], b, acc[qi][0], 0, 0, 0);
      acc[qi][1] = __builtin_amdgcn_mfma_f32_16x16x32_bf16(bank[1][ks], b, acc[qi][1], 0, 0, 0);
    }
  }
  // scan acc -> per-lane top-3, gated by 4-wide max
  // (C/D layout: row = tile*16 + grp*4 + rr, col = query l15)
#pragma unroll
  for (int vi = 0; vi < 2; ++vi) {
    const int rbase = (t0 + vi) * 16 + grp * 4;
#pragma unroll
    for (int qi = 0; qi < 4; ++qi) {
      const f32x4 a4 = acc[qi][vi];
      const float m01 = fmaxf(a4[0], a4[1]);
      const float m23 = fmaxf(a4[2], a4[3]);
      if (fmaxf(m01, m23) > v3[qi][2]) {
#pragma unroll
        for (int rr = 0; rr < 4; ++rr)
          ins3(a4[rr], rbase + rr, &v3[qi][0], &i3[qi][0]);
      }
    }
  }
}

__global__ __launch_bounds__(512, 2)
void score_kernel(const unsigned short* __restrict__ sw,
                  const unsigned short* __restrict__ qsw,
                  float2* __restrict__ cand) {
  __shared__ __align__(16) unsigned short qlds[8 * TILE_U];   // 81,920 B

  const int tid = threadIdx.x;
  const int wave = tid >> 6, lane = tid & 63;
  const int l15 = lane & 15, grp = lane >> 4;
  const int bid = blockIdx.x;
  const int rest = bid >> 3;
  const int m = rest & 3;
  const int s = (bid & 7) | ((rest >> 2) << 3);   // 0..127
  const int wr = wave >> 1, qhalf = wave & 1;

  // stage the 128-query B-panel (8 q-tiles) once
  {
    const uint4* src = (const uint4*)(qsw + (size_t)m * 8 * TILE_U);
    uint4* dst = (uint4*)qlds;
#pragma unroll
    for (int i = 0; i < 10; ++i) dst[tid + 512 * i] = src[tid + 512 * i];
  }
  __syncthreads();

  float v3[4][3]; int i3[4][3];
#pragma unroll
  for (int qi = 0; qi < 4; ++qi)
#pragma unroll
    for (int j = 0; j < 3; ++j) { v3[qi][j] = -1e30f; i3[qi][j] = 0; }

  const unsigned short* aw = sw + lane * 8;
  const unsigned short* bw = qlds + (size_t)qhalf * 4 * TILE_U + lane * 8;
  const int wt = s * 8 + wr * 2;                  // wave's first tile in stripe
  const int nit = (wt < 424) ? 25 : 24;           // 24*1024 + 424 = 25000

  s16x8 A0[2][10], A1[2][10];
  load_bank(A0, aw, (unsigned)wt * TILE_U);

  int it = 0;
  while (it + 1 < nit) {
    // prefetch pair it+1 into A1, compute pair it from A0
    load_bank(A1, aw, (unsigned)((it + 1) * 1024 + wt) * TILE_U);
    compute_pair(A0, bw, it * 1024 + wt, grp, v3, i3);
    // prefetch pair it+2 into A0 (clamped to valid tile when past end)
    {
      const int nt2 = (it + 2 < nit) ? (it + 2) * 1024 + wt : wt;
      load_bank(A0, aw, (unsigned)nt2 * TILE_U);
    }
    compute_pair(A1, bw, (it + 1) * 1024 + wt, grp, v3, i3);
    it += 2;
  }
  if (it < nit)
    compute_pair(A0, bw, it * 1024 + wt, grp, v3, i3);

  // merge 4 grp-lanes' top-3 -> union top-6, write 6 cand slots per
  // (query, stripe, rowpair)
#pragma unroll
  for (int qi = 0; qi < 4; ++qi) {
    float m0 = v3[qi][0], m1 = v3[qi][1], m2 = v3[qi][2];
    int   d0 = i3[qi][0], d1 = i3[qi][1], d2 = i3[qi][2];
    const int q = m * 128 + qhalf * 64 + qi * 16 + l15;
    float2* dst = cand + (size_t)q * NCAND + ((s * 4 + wr) * 6);
#pragma unroll
    for (int r = 0; r < 6; ++r) {
      float bv = m0; int bi = d0; int bl = grp;
      float ov = __shfl_xor(bv, 16, 64);
      int   oi = __shfl_xor(bi, 16, 64);
      int   ol = __shfl_xor(bl, 16, 64);
      if (ov > bv || (ov == bv && ol < bl)) { bv = ov; bi = oi; bl = ol; }
      ov = __shfl_xor(bv, 32, 64);
      oi = __shfl_xor(bi, 32, 64);
      ol = __shfl_xor(bl, 32, 64);
      if (ov > bv || (ov == bv && ol < bl)) { bv = ov; bi = oi; bl = ol; }
      if (bl == grp) { m0 = m1; d0 = d1; m1 = m2; d1 = d2; m2 = -1e30f; }
      if (r == grp || r == grp + 4) {
        float2 e; e.x = bv; e.y = __int_as_float(bi);
        dst[r] = e;
      }
    }
  }
}

// ---------------- P2: merge candidates, exact rescore, top-5 ----------------
__global__ __launch_bounds__(256)
void topk_kernel(const float* __restrict__ emb, const float* __restrict__ qf,
                 const float2* __restrict__ cand, float* __restrict__ out) {
  __shared__ float pV[256 * 6];
  __shared__ int   pI[256 * 6];
  __shared__ int   selI[32];
  __shared__ float resV[32];

  const int q = blockIdx.x;
  const int t = threadIdx.x;
  const float2* cq = cand + (size_t)q * NCAND;

  // per-thread top-6 over 3072/256 = 12 entries
  float bv[6]; int bi[6];
#pragma unroll
  for (int j = 0; j < 6; ++j) { bv[j] = -1e30f; bi[j] = -1; }
  for (int i = t; i < NCAND; i += 256) {
    const float2 e = cq[i];
    const float v = e.x;
    if (v > bv[5]) {
      bv[5] = v; bi[5] = __float_as_int(e.y);
#pragma unroll
      for (int j = 5; j > 0; --j) {
        if (bv[j] > bv[j - 1]) {
          const float tv2 = bv[j]; bv[j] = bv[j - 1]; bv[j - 1] = tv2;
          const int ti2 = bi[j]; bi[j] = bi[j - 1]; bi[j - 1] = ti2;
        }
      }
    }
  }
#pragma unroll
  for (int j = 0; j < 6; ++j) { pV[t * 6 + j] = bv[j]; pI[t * 6 + j] = bi[j]; }
  __syncthreads();

  // wave 0: select top-32 (approx values) from the 1536-entry pool
  if (t < 64) {
    for (int r = 0; r < 32; ++r) {
      float mv = -2e30f; int mp = 0;
      for (int i = t; i < 256 * 6; i += 64) {
        const float v = pV[i];
        if (v > mv) { mv = v; mp = i; }
      }
#pragma unroll
      for (int m = 1; m < 64; m <<= 1) {
        const float ov = __shfl_xor(mv, m, 64);
        const int   op = __shfl_xor(mp, m, 64);
        if (ov > mv) { mv = ov; mp = op; }
      }
      if (t == 0) { selI[r] = pI[mp]; pV[mp] = -2e30f; }
      __builtin_amdgcn_wave_barrier();
    }
  }
  __syncthreads();

  // exact fp32 rescore of 32 candidates, 8 threads each
  {
    const int j = t >> 3, sub = t & 7;
    const int id = selI[j];
    float dot = 0.f, sq = 0.f;
    if (id >= 0) {
      const f32x4* e4 = (const f32x4*)(emb + (size_t)id * DIM);
      const f32x4* q4 = (const f32x4*)(qf + (size_t)q * QFSTR);
      for (int f = sub; f < DIM / 4; f += 8) {
        const f32x4 ev = e4[f], qv = q4[f];
        dot += ev[0]*qv[0] + ev[1]*qv[1] + ev[2]*qv[2] + ev[3]*qv[3];
        sq  += ev[0]*ev[0] + ev[1]*ev[1] + ev[2]*ev[2] + ev[3]*ev[3];
      }
    }
#pragma unroll
    for (int m = 1; m < 8; m <<= 1) {
      dot += __shfl_xor(dot, m, 64);
      sq  += __shfl_xor(sq, m, 64);
    }
    if (sub == 0)
      resV[j] = (id >= 0 && sq > 0.f) ? (float)((double)dot / sqrt((double)sq)) : -2e30f;
  }
  __syncthreads();

  if (t == 0) {
#pragma unroll
    for (int r = 0; r < TOPK; ++r) {
      float mv = -3e30f; int mp = 0;
      for (int i = 0; i < 32; ++i) if (resV[i] > mv) { mv = resV[i]; mp = i; }
      out[q * TOPK + r] = mv;
      out[NQ * TOPK + q * TOPK + r] = (float)selI[mp];
      resV[mp] = -3e30f;
    }
  }
}

extern "C" void kernel_launch(void* const* d_in, const int* in_sizes, int n_in,
                              void* d_out, int out_size, void* d_ws, size_t ws_size,
                              hipStream_t stream) {
  (void)in_sizes; (void)n_in; (void)out_size; (void)ws_size;
  const float* emb = (const float*)d_in[0];
  const int* wid = (const int*)d_in[1];   // word_ids; d_in[2] (k=5) hardcoded
  float* out = (float*)d_out;

  // workspace layout (total 269,533,184 B):
  //   qsw  @ 0         : 32*5120*2   =    327,680
  //   qf   @ 327680    : 512*304*4   =    622,592
  //   cand @ 950272    : 512*3072*8  = 12,582,912
  //   sw   @ 13533184  : 25000*10240 = 256,000,000
  char* ws = (char*)d_ws;
  unsigned short* qsw = (unsigned short*)ws;
  float*  qf   = (float*)(ws + 327680);
  float2* cand = (float2*)(ws + 950272);
  unsigned short* sw = (unsigned short*)(ws + 13533184);

  qprep_kernel<<<NQ, 64, 0, stream>>>(emb, wid, qf, qsw);
  prenorm_kernel<<<VOCAB / 64, 256, 0, stream>>>(emb, sw);
  score_kernel<<<512, 512, 0, stream>>>(sw, qsw, cand);
  topk_kernel<<<NQ, 256, 0, stream>>>(emb, qf, cand, out);
}